// Round 3
// baseline (1322.848 us; speedup 1.0000x reference)
//
#include <hip/hip_runtime.h>
#include <hip/hip_bf16.h>

#define NB 512
#define KD 128
#define VD 64
#define NKEYS 500000
#define TOPK 16
#define CH 1024
#define NCHUNK 489            // ceil(500000/1024)
#define NKEYSP (NCHUNK*CH)    // 500736 padded rows in bf16 key buffer
#define CPC 8                 // candidates kept per (query, chunk)
#define NCAND (NCHUNK*CPC)    // 3912 candidates per query
#define CBUF 64               // merge rescore buffer
#define JCAND 16              // ceil(NCAND/256) per-thread candidates in merge

typedef __attribute__((ext_vector_type(8))) short bf8s;
typedef __attribute__((ext_vector_type(4))) float f4;
typedef __attribute__((ext_vector_type(4))) int i4;
typedef __attribute__((ext_vector_type(4))) unsigned u4;

__device__ __forceinline__ unsigned f2bf(float x) {
  union { float f; unsigned u; } v; v.f = x;
  return (v.u + 0x7fffu + ((v.u >> 16) & 1u)) >> 16;   // RNE fp32->bf16
}

// ---------------- Kernel 1: normalize queries, fold in 1/temperature = 4 ----
__global__ __launch_bounds__(128) void qnorm_kernel(const float* __restrict__ q,
                                                    float* __restrict__ qn_f,
                                                    short* __restrict__ qn_bf) {
  int b = blockIdx.x, t = threadIdx.x;
  float x = q[b*KD + t];
  float s = x * x;
  #pragma unroll
  for (int o = 32; o > 0; o >>= 1) s += __shfl_down(s, o);
  __shared__ float p[2];
  if ((t & 63) == 0) p[t >> 6] = s;
  __syncthreads();
  float norm = sqrtf(p[0] + p[1]);
  norm = fmaxf(norm, 1e-8f);
  float v = x * (4.0f / norm);        // qn * (1/0.25); *4 is exact in fp32
  qn_f[b*KD + t] = v;
  qn_bf[b*KD + t] = (short)f2bf(v);
}

// ---------------- Kernel 1b: keys fp32 -> bf16, once (memory-bound) --------
// 500000*128 floats, 8 per thread, exact grid (31250 blocks), no bound check.
__global__ __launch_bounds__(256) void kconv_kernel(const float* __restrict__ keys,
                                                    unsigned short* __restrict__ kbf) {
  size_t i = ((size_t)blockIdx.x*256 + threadIdx.x)*8;
  f4 a = *(const f4*)(keys + i);
  f4 b = *(const f4*)(keys + i + 4);
  u4 p;
  p[0] = f2bf(a[0]) | (f2bf(a[1]) << 16);
  p[1] = f2bf(a[2]) | (f2bf(a[3]) << 16);
  p[2] = f2bf(b[0]) | (f2bf(b[1]) << 16);
  p[3] = f2bf(b[2]) | (f2bf(b[3]) << 16);
  *(u4*)(kbf + i) = p;
}

// ---------------- Kernel 2: barrier-free MFMA scores + per-chunk top-8 ------
// MODE 0: keys pre-converted to bf16 (direct fragment loads, zero convert VALU)
// MODE 1: fallback, in-kernel fp32->bf16 convert (used only if ws too small)
// Scores carry their key-index in the low 8 mantissa bits -> index-free scan.
template<int MODE>
__global__ __launch_bounds__(256) void score_filter_kernel(
    const float* __restrict__ keysf, const unsigned short* __restrict__ keysb,
    const short* __restrict__ qn_bf,
    float* __restrict__ cand_val, int* __restrict__ cand_idx) {
  __shared__ float slds[4*64*20];          // per-wave patches, stride 20 (16B ok)
  const int bid = blockIdx.x;
  const int chunk = (bid & 7) + 8*(bid >> 6);   // 8 blocks/chunk share XCD residue
  const int gy    = (bid >> 3) & 7;
  if (chunk >= NCHUNK) return;
  const int tid  = threadIdx.x;
  const int wave = tid >> 6, lane = tid & 63;
  const int col  = lane & 15, quad = lane >> 4;

  // A fragments: A[m = query][k], queries qbase..qbase+63, held for whole chunk
  bf8s afrag[4][4];
  const int qbase = gy*64;
  #pragma unroll
  for (int mt = 0; mt < 4; mt++)
    #pragma unroll
    for (int ks = 0; ks < 4; ks++)
      afrag[mt][ks] = *(const bf8s*)(qn_bf + (qbase + mt*16 + col)*KD + ks*32 + quad*8);

  float tv0=-1e30f, tv1=-1e30f, tv2=-1e30f, tv3=-1e30f;   // packed scores, desc
  const int k0 = chunk*CH + wave*256;      // this wave's private key range
  const bool tailw = (k0 + 256 > NKEYS);   // wave-uniform: range has OOB keys

  float* wp = slds + wave*1280;            // wave patch [64 rows][20]
  const float* sp = wp + lane*20;          // this lane's (query's) row

  bf8s bfA[4], bfB[4];                     // named double buffers (static idx)
  f4   xbA[8], xbB[8];

  // prologue: load tile 0 into buffer A
  if constexpr (MODE == 0) {
    const unsigned short* kp = keysb + (size_t)(k0 + col)*KD + quad*8;
    #pragma unroll
    for (int ks = 0; ks < 4; ks++) bfA[ks] = *(const bf8s*)(kp + ks*32);
  } else {
    int r = min(k0 + col, NKEYS-1);
    const float* kp = keysf + (size_t)r*KD + quad*8;
    #pragma unroll
    for (int ks = 0; ks < 4; ks++) {
      xbA[2*ks]   = *(const f4*)(kp + ks*32);
      xbA[2*ks+1] = *(const f4*)(kp + ks*32 + 4);
    }
  }

  // per-tile body; consumes bufC, prefetches into bufN
  auto tile_body = [&](int t16, bf8s (&bfC)[4], bf8s (&bfN)[4],
                       f4 (&xbC)[8], f4 (&xbN)[8]) {
    const int nb16 = k0 + t16*16;
    // prefetch next tile (stays in flight under MFMA+LDS+scan; no barriers)
    if (t16 < 15) {
      if constexpr (MODE == 0) {
        const unsigned short* kp = keysb + (size_t)(nb16 + 16 + col)*KD + quad*8;
        #pragma unroll
        for (int ks = 0; ks < 4; ks++) bfN[ks] = *(const bf8s*)(kp + ks*32);
      } else {
        int r = min(nb16 + 16 + col, NKEYS-1);
        const float* kp = keysf + (size_t)r*KD + quad*8;
        #pragma unroll
        for (int ks = 0; ks < 4; ks++) {
          xbN[2*ks]   = *(const f4*)(kp + ks*32);
          xbN[2*ks+1] = *(const f4*)(kp + ks*32 + 4);
        }
      }
    }
    bf8s bcur[4];
    if constexpr (MODE == 0) {
      #pragma unroll
      for (int ks = 0; ks < 4; ks++) bcur[ks] = bfC[ks];
    } else {
      #pragma unroll
      for (int ks = 0; ks < 4; ks++) {
        union { unsigned u[4]; bf8s b; } t;
        f4 a = xbC[2*ks], b = xbC[2*ks+1];
        t.u[0] = f2bf(a[0]) | (f2bf(a[1]) << 16);
        t.u[1] = f2bf(a[2]) | (f2bf(a[3]) << 16);
        t.u[2] = f2bf(b[0]) | (f2bf(b[1]) << 16);
        t.u[3] = f2bf(b[2]) | (f2bf(b[3]) << 16);
        bcur[ks] = t.b;
      }
    }
    f4 acc[4];
    #pragma unroll
    for (int mt = 0; mt < 4; mt++) { acc[mt][0]=0.f; acc[mt][1]=0.f; acc[mt][2]=0.f; acc[mt][3]=0.f; }
    #pragma unroll
    for (int ks = 0; ks < 4; ks++)
      #pragma unroll
      for (int mt = 0; mt < 4; mt++)
        acc[mt] = __builtin_amdgcn_mfma_f32_16x16x32_bf16(afrag[mt][ks], bcur[ks], acc[mt], 0, 0, 0);
    // write scores with key-in-quarter packed into low 8 mantissa bits.
    // C/D layout: col = lane&15 (key), row = quad*4 + reg (query) [m89]
    const unsigned kbase = (unsigned)(t16*16 + col);   // 0..255, disjoint bits
    #pragma unroll
    for (int mt = 0; mt < 4; mt++)
      #pragma unroll
      for (int rg = 0; rg < 4; rg++) {
        float v = acc[mt][rg];
        if (tailw) v = (nb16 + col < NKEYS) ? v : -1e30f;  // mask OOB keys
        unsigned pv = (__float_as_uint(v) & 0xFFFFFF00u) | kbase;
        wp[(mt*16 + quad*4 + rg)*20 + col] = __uint_as_float(pv);
      }
    // scan: lane owns query row; index-free top-4 on packed floats
    #pragma unroll
    for (int j = 0; j < 4; j++) {
      f4 g = *(const f4*)(sp + j*4);
      #pragma unroll
      for (int c = 0; c < 4; c++) {
        float v = g[c];
        if (v > tv3) {
          if (v > tv0)      { tv3=tv2; tv2=tv1; tv1=tv0; tv0=v; }
          else if (v > tv1) { tv3=tv2; tv2=tv1; tv1=v; }
          else if (v > tv2) { tv3=tv2; tv2=v; }
          else              { tv3=v; }
        }
      }
    }
  };

  #pragma unroll 1
  for (int t2 = 0; t2 < 8; t2++) {
    tile_body(2*t2,     bfA, bfB, xbA, xbB);
    tile_body(2*t2 + 1, bfB, bfA, xbB, xbA);
  }

  // ---- block combine: 4 waves x top-4 -> per-query top-8 (2 barriers total)
  __syncthreads();                          // all patch reads done
  float* fv = slds;                         // [4 waves][64 lanes][4] packed
  const int pb = wave*256 + lane*4;
  fv[pb+0]=tv0; fv[pb+1]=tv1; fv[pb+2]=tv2; fv[pb+3]=tv3;
  __syncthreads();
  if (tid < 64) {
    float bv[8]; int bi[8];
    #pragma unroll
    for (int k = 0; k < 8; k++) { bv[k] = -1e30f; bi[k] = 0; }
    #pragma unroll
    for (int w = 0; w < 4; w++) {
      const int kw = chunk*CH + w*256;
      #pragma unroll
      for (int j = 0; j < 4; j++) {
        float v = fv[w*256 + tid*4 + j];
        int  ix = kw + (int)(__float_as_uint(v) & 0xFFu);   // decode key index
        if (v > bv[7]) {
          bv[7] = v; bi[7] = ix;
          #pragma unroll
          for (int s = 7; s > 0; s--)
            if (bv[s] > bv[s-1]) {
              float tv = bv[s]; bv[s] = bv[s-1]; bv[s-1] = tv;
              int   ti = bi[s]; bi[s] = bi[s-1]; bi[s-1] = ti;
            }
        }
      }
    }
    const size_t o = ((size_t)(qbase + tid)*NCHUNK + chunk)*CPC;
    f4 v0; v0[0]=bv[0]; v0[1]=bv[1]; v0[2]=bv[2]; v0[3]=bv[3];
    f4 v1; v1[0]=bv[4]; v1[1]=bv[5]; v1[2]=bv[6]; v1[3]=bv[7];
    i4 j0; j0[0]=bi[0]; j0[1]=bi[1]; j0[2]=bi[2]; j0[3]=bi[3];
    i4 j1; j1[0]=bi[4]; j1[1]=bi[5]; j1[2]=bi[6]; j1[3]=bi[7];
    *(f4*)(cand_val + o)     = v0;
    *(f4*)(cand_val + o + 4) = v1;
    *(i4*)(cand_idx + o)     = j0;
    *(i4*)(cand_idx + o + 4) = j1;
  }
}

// ---------------- Kernel 3: radix threshold-select -> exact fp32 rescore ----
__global__ __launch_bounds__(256) void merge_rescore_kernel(
    const float* __restrict__ qn_f, const float* __restrict__ keys,
    const float* __restrict__ values, const float* __restrict__ cand_val,
    const int* __restrict__ cand_idx, float* __restrict__ out) {
  const int b = blockIdx.x, t = threadIdx.x;
  const int lane = t & 63, wave = t >> 6;
  __shared__ float qs[KD];
  __shared__ unsigned hist[256];
  __shared__ int wtot[4];
  __shared__ int s_bound, s_above, s_bcnt, s_cnt;
  __shared__ float rv[CBUF]; __shared__ int ri[CBUF];
  __shared__ float sval[TOPK]; __shared__ int sidx[TOPK]; __shared__ float sw[TOPK];

  if (t < KD) qs[t] = qn_f[b*KD + t];

  // per-thread JCAND candidates, fp32 value -> order-preserving u32
  unsigned u[JCAND]; int id[JCAND];
  #pragma unroll
  for (int j = 0; j < JCAND; j++) {
    int i = t + j*256;
    if (i < NCAND) {
      union { float f; unsigned q; } cvt; cvt.f = cand_val[(size_t)b*NCAND + i];
      unsigned m = cvt.q;
      m = (m & 0x80000000u) ? ~m : (m | 0x80000000u);
      u[j] = m; id[j] = cand_idx[(size_t)b*NCAND + i];
    } else { u[j] = 0u; id[j] = -1; }
  }

  // radix threshold select over top 24 bits, 8 bits per pass
  unsigned prefix = 0; int above = 0; unsigned thr = 0; bool done = false;
  #pragma unroll 1
  for (int pass = 0; pass < 3 && !done; pass++) {
    const int shift = 24 - 8*pass;
    hist[t] = 0u;
    __syncthreads();
    #pragma unroll
    for (int j = 0; j < JCAND; j++) {
      bool ok = (pass == 0) || ((u[j] >> (shift + 8)) == prefix);
      if (ok) atomicAdd(&hist[(u[j] >> shift) & 255u], 1u);
    }
    __syncthreads();
    int h = (int)hist[t];
    int s = h;
    #pragma unroll
    for (int o = 1; o < 64; o <<= 1) {
      int nv = __shfl_down(s, o);
      if (lane + o < 64) s += nv;
    }
    if (lane == 0) wtot[wave] = s;
    __syncthreads();
    int add = 0;
    for (int g = wave + 1; g < 4; g++) add += wtot[g];
    int S = s + add;                          // count of cands with bin >= t
    if (above + S >= 32 && above + S - h < 32) {
      s_bound = t; s_above = above + S - h; s_bcnt = h;
    }
    __syncthreads();
    prefix = (prefix << 8) | (unsigned)s_bound;
    above  = s_above;
    if (s_above + s_bcnt <= CBUF || pass == 2) { thr = prefix << shift; done = true; }
    __syncthreads();
  }

  // collect ids with u >= thr
  if (t == 0) s_cnt = 0;
  __syncthreads();
  #pragma unroll
  for (int j = 0; j < JCAND; j++) {
    if (id[j] >= 0 && u[j] >= thr) {
      int p = atomicAdd(&s_cnt, 1);
      if (p < CBUF) ri[p] = id[j];
    }
  }
  __syncthreads();
  const int C = min(s_cnt, CBUF);
  if (t >= C && t < CBUF) ri[t] = 0x7fffffff;
  __syncthreads();

  // exact fp32 rescore: 4 threads per candidate, 32 dims each
  {
    int c = t >> 2, dg = t & 3;
    float part = 0.f;
    if (c < C) {
      const float* kr = keys + (size_t)ri[c]*KD + dg*32;
      #pragma unroll
      for (int j = 0; j < 32; j++) part += kr[j] * qs[dg*32 + j];
    }
    part += __shfl_down(part, 2, 4);
    part += __shfl_down(part, 1, 4);
    if (dg == 0) rv[c] = (c < C) ? part : -1e30f;
  }
  __syncthreads();

  // exact rank (desc value, tie -> lower index, matching jax.lax.top_k)
  if (t < CBUF) {
    float v = rv[t]; int idx = ri[t];
    int rank = 0;
    for (int j = 0; j < CBUF; j++) {
      float vj = rv[j]; int ij = ri[j];
      rank += (vj > v) || (vj == v && ij < idx);
    }
    if (rank < TOPK) { sval[rank] = v; sidx[rank] = idx; }
  }
  __syncthreads();

  // softmax with +eps denominator; write topw and topidx (as float)
  if (t < TOPK) {
    float m = sval[0];
    float e = expf(sval[t] - m);
    float s2 = e;
    #pragma unroll
    for (int o = 8; o > 0; o >>= 1) s2 += __shfl_down(s2, o, 16);
    s2 = __shfl(s2, 0, 16);
    float w = e / (s2 + 1e-8f);
    sw[t] = w;
    out[NB*VD + b*TOPK + t] = w;                        // topw
    out[NB*VD + NB*TOPK + b*TOPK + t] = (float)sidx[t]; // topidx as float
  }
  __syncthreads();

  // retrieved = sum_k w_k * values[idx_k]
  if (t < VD) {
    float acc = 0.f;
    #pragma unroll
    for (int k = 0; k < TOPK; k++) acc += sw[k] * values[(size_t)sidx[k]*VD + t];
    out[b*VD + t] = acc;
  }
}

extern "C" void kernel_launch(void* const* d_in, const int* in_sizes, int n_in,
                              void* d_out, int out_size, void* d_ws, size_t ws_size,
                              hipStream_t stream) {
  const float* queries = (const float*)d_in[0];
  const float* keys    = (const float*)d_in[1];
  const float* values  = (const float*)d_in[2];
  float* out = (float*)d_out;

  char* ws = (char*)d_ws;
  float* qn_f  = (float*)ws;                                   // 512*128 f32
  short* qn_bf = (short*)(ws + (size_t)NB*KD*4);               // 512*128 bf16
  float* cand_val = (float*)(ws + (size_t)NB*KD*4 + (size_t)NB*KD*2);
  int*   cand_idx = (int*)((char*)cand_val + (size_t)NB*NCAND*sizeof(float));
  unsigned short* kbf = (unsigned short*)((char*)cand_idx + (size_t)NB*NCAND*sizeof(int));

  const size_t need = (size_t)NB*KD*4 + (size_t)NB*KD*2
                    + (size_t)NB*NCAND*8 + (size_t)NKEYSP*KD*2;

  qnorm_kernel<<<NB, KD, 0, stream>>>(queries, qn_f, qn_bf);
  if (ws_size >= need) {
    kconv_kernel<<<(NKEYS*KD)/(256*8), 256, 0, stream>>>(keys, kbf);
    score_filter_kernel<0><<<62*64, 256, 0, stream>>>(keys, kbf, qn_bf, cand_val, cand_idx);
  } else {
    score_filter_kernel<1><<<62*64, 256, 0, stream>>>(keys, nullptr, qn_bf, cand_val, cand_idx);
  }
  merge_rescore_kernel<<<NB, 256, 0, stream>>>(qn_f, keys, values, cand_val, cand_idx, out);
}